// Round 11
// baseline (53.694 us; speedup 1.0000x reference)
//
#include <hip/hip_runtime.h>
#include <hip/hip_bf16.h>
#include <math.h>
#include <stdint.h>

#define B 8
#define L 256
#define DM 512
#define NH 16
#define APO 128
#define VOC 128
#define EMB (L * B * DM)   // 1048576 floats

typedef __attribute__((ext_vector_type(8))) short short8v;   // 8 bf16 (4 VGPR)
typedef __attribute__((ext_vector_type(4))) float float4v;   // MFMA C/D

// ws layout (main path):
//   float[0..255]    : unused (fallback-compat offsets)
//   float[256..1280) : wsB = lw' B-fragments, ushort[2048] (bf16, mfma frag layout)
//   byte 6144 ..     : packed table, 16384 rows x 512 B:
//                      row r, chunk cc (16 k), pieces: [0,1]=w' halves, [2,3]=b' halves
//                      w' = w * beta/sigma_k ; b' = (b - mean_k) * beta/sigma_k  (bf16)
#define WSB_FOFF   256
#define PACK_BOFF  6144
#define PACK_BYTES (16384 * 512)
#define WS_NEED    ((size_t)PACK_BOFF + (size_t)PACK_BYTES)

__device__ __forceinline__ void g2lds16(const void* g, void* l) {
    __builtin_amdgcn_global_load_lds(
        (const __attribute__((address_space(1))) unsigned int*)g,
        (__attribute__((address_space(3))) unsigned int*)l, 16, 0, 0);
}

// ================= main path: setup (emb + table conversion + wsB) =============
__global__ __launch_bounds__(256) void setup_kernel(const int* __restrict__ atoms,
                                                    const int* __restrict__ chirals,
                                                    const float* __restrict__ atype,
                                                    const float* __restrict__ chiral,
                                                    const float* __restrict__ wtab,
                                                    const float* __restrict__ btab,
                                                    const float* __restrict__ means,
                                                    const float* __restrict__ stds,
                                                    const float* __restrict__ lin_w,
                                                    float* __restrict__ ws,
                                                    float* __restrict__ out) {
    int bid = blockIdx.x;          // 0..2047
    int t = threadIdx.x;
    const float beta = sqrtf(0.5f * 1.4426950408889634f);  // exp(-.5x^2)=exp2(-(x*beta)^2)
    const float gscale = 0.3989422804014327f;              // 1/sqrt(2*pi)

    // ---- emb for (bi,li) = bid (threads 0..127)
    if (t < 128) {
        int bi = bid >> 8, li = bid & 255;
        int a = atoms[bi * L + li];
        int c = chirals[bi * L + li];
        const float4* va = (const float4*)(atype + (size_t)a * DM);
        const float4* vc = (const float4*)(chiral + (size_t)c * DM);
        float4* vo = (float4*)(out + ((size_t)li * B + bi) * DM);
        float4 x = va[t], y = vc[t];
        x.x += y.x; x.y += y.y; x.z += y.z; x.w += y.w;
        vo[t] = x;
    }

    // ---- wsB (block 0): lw' in mfma_f32_16x16x32_bf16 B-frag layout
    if (bid == 0) {
        unsigned short* wsB = (unsigned short*)(ws + WSB_FOFF);
        for (int idx = t; idx < 4 * 64 * 8; idx += 256) {
            int c2 = idx >> 9;
            int lane = (idx >> 3) & 63;
            int e = idx & 7;
            int k = c2 * 32 + ((lane >> 4) << 3) + e;
            int h = lane & 15;
            float sigma = fabsf(stds[k]) + 1e-5f;
            float v = lin_w[k * NH + h] * (gscale / sigma);
            __hip_bfloat16 hb = __float2bfloat16(v);
            wsB[idx] = *reinterpret_cast<unsigned short*>(&hb);
        }
    }

    // ---- table conversion: one 16B piece (8 k) per thread
    int g = bid * 256 + t;          // 0..524287
    int row = g >> 5;               // 0..16383
    int p32 = g & 31;
    int cc = p32 >> 2, pp = p32 & 3;
    int k0 = cc * 16 + (pp & 1) * 8;
    const float* src = (pp < 2) ? wtab : btab;
    const float4* s4 = (const float4*)(src + (size_t)row * APO + k0);
    float4 v0 = s4[0], v1 = s4[1];
    const float* vv = (const float*)&v0;
    short8v o;
    #pragma unroll
    for (int e = 0; e < 8; ++e) {
        int k = k0 + e;
        float x = (e < 4) ? vv[e] : ((const float*)&v1)[e - 4];
        float sigma = fabsf(stds[k]) + 1e-5f;
        float ia = beta / sigma;
        float val = (pp < 2) ? x * ia : (x - means[k]) * ia;
        __hip_bfloat16 hb = __float2bfloat16(val);
        o[e] = *reinterpret_cast<short*>(&hb);
    }
    char* pk = (char*)ws + PACK_BOFF;
    *(short8v*)(pk + (size_t)row * 512 + cc * 64 + pp * 16) = o;
}

// ================= main path: pair kernel ======================================
// Register-staged: each lane directly gathers the 16B w'/b' pieces its own
// MFMA A-fragments need (rows 16q+(l&15), k-grp m=l>>4). No staging LDS at
// all; rounds 0-2 prefetched before the loop, round 3 after round 0 ->
// >=2 rounds of compute cover each gather's latency; compiler emits exact
// per-register waits.
__global__ __launch_bounds__(256) void pair_kernel_bf16(const int* __restrict__ atoms,
                                                        const float* __restrict__ coords,
                                                        const int* __restrict__ bonds,
                                                        const float* __restrict__ bond_emb,
                                                        const float* __restrict__ lin_b,
                                                        const float* __restrict__ ws,
                                                        float* __restrict__ out) {
    __shared__ float be[32][17];
    __shared__ __align__(16) float cbuf_s[4][16 * 68];   // per-wave C transpose

    int t = threadIdx.x;            // j
    int bid = blockIdx.x;           // bi*256 + i
    int bi = bid >> 8, i = bid & 255;
    int w = t >> 6, l = t & 63;

    for (int idx = t; idx < 32 * NH; idx += 256)
        be[idx >> 4][idx & 15] = bond_emb[idx];
    __syncthreads();                // only block barrier

    int a_i = atoms[bi * L + i];

    float cix = coords[((size_t)bi * L + i) * 3 + 0];
    float ciy = coords[((size_t)bi * L + i) * 3 + 1];
    float ciz = coords[((size_t)bi * L + i) * 3 + 2];
    float cjx = coords[((size_t)bi * L + t) * 3 + 0];
    float cjy = coords[((size_t)bi * L + t) * 3 + 1];
    float cjz = coords[((size_t)bi * L + t) * 3 + 2];
    float dx = cjx - cix, dy = cjy - ciy, dz = cjz - ciz;
    float s2 = dx * dx + dy * dy + dz * dz;
    float d = (s2 > 0.0f) ? sqrtf(s2) : 0.0f;

    // d of the 4 rows this lane's A-frags cover (lane r of the wave = row r)
    int dbits = __float_as_int(d);
    float dval[4];
    #pragma unroll
    for (int q = 0; q < 4; ++q)
        dval[q] = __int_as_float(
            __builtin_amdgcn_ds_bpermute((q * 16 + (l & 15)) * 4, dbits));

    // per-q base: row's packed bytes + this lane's k-group sub-offset.
    // round r: w piece at base+r*128, b piece at base+r*128+32.
    int m = l >> 4;
    const char* pk = (const char*)ws + PACK_BOFF;
    const char* base[4];
    #pragma unroll
    for (int q = 0; q < 4; ++q) {
        int ajr = atoms[bi * L + (w * 64 + q * 16 + (l & 15))];
        int row = ajr * VOC + a_i;
        base[q] = pk + (size_t)row * 512 + (m >> 1) * 64 + (m & 1) * 16;
    }

    const unsigned short* wsB = (const unsigned short*)(ws + WSB_FOFF);
    short8v bfrag[4];
    #pragma unroll
    for (int c2 = 0; c2 < 4; ++c2)
        bfrag[c2] = *(const short8v*)(wsB + ((size_t)c2 * 64 + l) * 8);

    float4v acc[4];
    #pragma unroll
    for (int q = 0; q < 4; ++q) { float4v z = {0, 0, 0, 0}; acc[q] = z; }

    // register staging: [round][q], fully statically indexed (unrolled)
    uint4 wv[4][4], bv[4][4];
    #pragma unroll
    for (int r = 0; r < 3; ++r) {
        #pragma unroll
        for (int q = 0; q < 4; ++q) {
            wv[r][q] = *(const uint4*)(base[q] + r * 128);
            bv[r][q] = *(const uint4*)(base[q] + r * 128 + 32);
        }
    }

    #pragma unroll
    for (int r = 0; r < 4; ++r) {
        // gauss + MFMA: af elem e = bf16(exp2(-(w'*d+b')^2)), k = r*32 + m*8 + e
        #pragma unroll
        for (int q = 0; q < 4; ++q) {
            float dq = dval[q];
            short8v af;
            #pragma unroll
            for (int e2 = 0; e2 < 4; ++e2) {
                unsigned wd = ((const unsigned*)&wv[r][q])[e2];
                unsigned bd = ((const unsigned*)&bv[r][q])[e2];
                float wl = __uint_as_float(wd << 16);
                float wh = __uint_as_float(wd & 0xffff0000u);
                float bl = __uint_as_float(bd << 16);
                float bh = __uint_as_float(bd & 0xffff0000u);
                float tl = fmaf(wl, dq, bl);
                float th = fmaf(wh, dq, bh);
                float gl = __builtin_amdgcn_exp2f(-(tl * tl));
                float gh = __builtin_amdgcn_exp2f(-(th * th));
                __hip_bfloat16 hl = __float2bfloat16(gl);
                __hip_bfloat16 hh = __float2bfloat16(gh);
                af[2 * e2]     = *reinterpret_cast<short*>(&hl);
                af[2 * e2 + 1] = *reinterpret_cast<short*>(&hh);
            }
            acc[q] = __builtin_amdgcn_mfma_f32_16x16x32_bf16(af, bfrag[r], acc[q], 0, 0, 0);
        }
        if (r == 0) {               // issue round 3 under rounds 1-2 compute
            #pragma unroll
            for (int q = 0; q < 4; ++q) {
                wv[3][q] = *(const uint4*)(base[q] + 3 * 128);
                bv[3][q] = *(const uint4*)(base[q] + 3 * 128 + 32);
            }
        }
    }

    // ---- epilogue: transpose C through per-wave LDS buffer.
    // C layout (m89): col h = l&15, row j = 16q + (l>>4)*4 + reg.
    int a_j = atoms[bi * L + t];
    int bvd = bonds[(((size_t)bi * L) + i) * L + t];
    float* cbuf = cbuf_s[w];
    {
        int h = l & 15, jg = l >> 4;
        #pragma unroll
        for (int q = 0; q < 4; ++q)
            *(float4v*)(cbuf + h * 68 + q * 16 + jg * 4) = acc[q];
    }
    asm volatile("s_waitcnt lgkmcnt(0)" ::: "memory");
    __builtin_amdgcn_sched_barrier(0);

    size_t obase = (((size_t)bi * NH) * L + i) * L + t;
    // PAD column -> most-negative FINITE bf16 (0xff7f0000); survives harness bf16 cast.
    float ninf = __uint_as_float(0xff7f0000u);
    bool pad = (a_j == 0);
    #pragma unroll
    for (int h = 0; h < NH; ++h) {
        float v = cbuf[h * 68 + l] + lin_b[h] + be[bvd][h];
        out[obase + (size_t)h * L * L] = pad ? ninf : v;
    }
}

// ================= fallback path (r6, verified) ================================
__global__ __launch_bounds__(128) void emb_kernel(const int* __restrict__ atoms,
                                                  const int* __restrict__ chirals,
                                                  const float* __restrict__ atype,
                                                  const float* __restrict__ chiral,
                                                  float* __restrict__ out) {
    int bid = blockIdx.x;
    int bi = bid >> 8, li = bid & 255;
    int a = atoms[bi * L + li];
    int c = chirals[bi * L + li];
    const float4* va = (const float4*)(atype + (size_t)a * DM);
    const float4* vc = (const float4*)(chiral + (size_t)c * DM);
    float4* vo = (float4*)(out + ((size_t)li * B + bi) * DM);
    int t = threadIdx.x;
    float4 x = va[t], y = vc[t];
    x.x += y.x; x.y += y.y; x.z += y.z; x.w += y.w;
    vo[t] = x;
}

__global__ __launch_bounds__(256) void prep_kernel(const float* __restrict__ means,
                                                   const float* __restrict__ stds,
                                                   const float* __restrict__ lin_w,
                                                   float* __restrict__ ws) {
    int t = threadIdx.x;
    const float beta = sqrtf(0.5f * 1.4426950408889634f);
    const float gscale = 0.3989422804014327f;
    if (t < APO) {
        float sigma = fabsf(stds[t]) + 1e-5f;
        float inv = 1.0f / sigma;
        ws[t] = inv * beta;
        ws[APO + t] = -means[t] * inv * beta;
    }
    unsigned short* wsB = (unsigned short*)(ws + 2 * APO);
    for (int idx = t; idx < 4 * 64 * 8; idx += 256) {
        int c2 = idx >> 9;
        int lane = (idx >> 3) & 63;
        int e = idx & 7;
        int k = c2 * 32 + ((lane >> 4) << 3) + e;
        int h = lane & 15;
        float sigma = fabsf(stds[k]) + 1e-5f;
        float v = lin_w[k * NH + h] * (gscale / sigma);
        __hip_bfloat16 hb = __float2bfloat16(v);
        wsB[idx] = *reinterpret_cast<unsigned short*>(&hb);
    }
}

__global__ __launch_bounds__(256) void pair_kernel_f32(const int* __restrict__ atoms,
                                                       const float* __restrict__ coords,
                                                       const int* __restrict__ bonds,
                                                       const float* __restrict__ wtab,
                                                       const float* __restrict__ btab,
                                                       const float* __restrict__ bond_emb,
                                                       const float* __restrict__ lin_b,
                                                       const float* __restrict__ ws,
                                                       float* __restrict__ out) {
    __shared__ float be[32][17];
    __shared__ __align__(16) char lds_raw[32 * 1024];
    __shared__ __align__(16) char lds_g[16 * 1024];

    int t = threadIdx.x;
    int bid = blockIdx.x;
    int bi = bid >> 8, i = bid & 255;
    int w = t >> 6, l = t & 63;

    for (int idx = t; idx < 32 * NH; idx += 256)
        be[idx >> 4][idx & 15] = bond_emb[idx];
    __syncthreads();

    int a_i = atoms[bi * L + i];
    int a_j = atoms[bi * L + t];

    float cix = coords[((size_t)bi * L + i) * 3 + 0];
    float ciy = coords[((size_t)bi * L + i) * 3 + 1];
    float ciz = coords[((size_t)bi * L + i) * 3 + 2];
    float cjx = coords[((size_t)bi * L + t) * 3 + 0];
    float cjy = coords[((size_t)bi * L + t) * 3 + 1];
    float cjz = coords[((size_t)bi * L + t) * 3 + 2];
    float dx = cjx - cix, dy = cjy - ciy, dz = cjz - ciz;
    float s2 = dx * dx + dy * dy + dz * dz;
    float d = (s2 > 0.0f) ? sqrtf(s2) : 0.0f;

    char* ldsW = lds_raw + (size_t)w * 8192;
    char* ldsB_ = ldsW + 4096;
    char* gbase = lds_g + (size_t)w * 4096;
    const char* wt = (const char*)wtab;
    const char* bt = (const char*)btab;
    size_t goff[4];
    #pragma unroll
    for (int q = 0; q < 4; ++q) {
        int r = q * 16 + (l >> 2);
        int ajr = atoms[bi * L + (w * 64 + r)];
        int row = ajr * VOC + a_i;
        int piece = (l & 3) ^ ((r >> 1) & 3);
        goff[q] = (size_t)row * (APO * 4) + (size_t)piece * 16;
    }
    int ss = (l >> 1) & 3;

    const float* ia = ws;
    const float* c2c = ws + APO;
    const unsigned short* wsB = (const unsigned short*)(ws + 2 * APO);
    short8v bfrag[4];
    #pragma unroll
    for (int c2 = 0; c2 < 4; ++c2)
        bfrag[c2] = *(const short8v*)(wsB + ((size_t)c2 * 64 + l) * 8);

    float4v acc[4];
    #pragma unroll
    for (int q = 0; q < 4; ++q) { float4v z = {0,0,0,0}; acc[q] = z; }

    #pragma unroll
    for (int c2i = 0; c2i < 4; ++c2i) {
        short8v g8[4];
        #pragma unroll
        for (int s = 0; s < 2; ++s) {
            int cc = c2i * 2 + s;
            #pragma unroll
            for (int q = 0; q < 4; ++q) {
                g2lds16(wt + goff[q] + cc * 64, ldsW + q * 1024);
                g2lds16(bt + goff[q] + cc * 64, ldsB_ + q * 1024);
            }
            asm volatile("s_waitcnt vmcnt(0)" ::: "memory");
            __builtin_amdgcn_sched_barrier(0);
            #pragma unroll
            for (int p = 0; p < 4; ++p) {
                int u = p ^ ss;
                float4 w4 = *(const float4*)(ldsW + l * 64 + u * 16);
                float4 b4 = *(const float4*)(ldsB_ + l * 64 + u * 16);
                const float* wp = (const float*)&w4;
                const float* bp = (const float*)&b4;
                #pragma unroll
                for (int uu = 0; uu < 4; ++uu) {
                    int kk = s * 16 + p * 4 + uu;
                    int k = c2i * 32 + kk;
                    float tt = fmaf(wp[uu], d, bp[uu]);
                    tt = fmaf(tt, ia[k], c2c[k]);
                    float g = __builtin_amdgcn_exp2f(-(tt * tt));
                    __hip_bfloat16 hb = __float2bfloat16(g);
                    g8[kk >> 3][kk & 7] = *reinterpret_cast<short*>(&hb);
                }
            }
            asm volatile("s_waitcnt lgkmcnt(0)" ::: "memory");
            __builtin_amdgcn_sched_barrier(0);
        }
        int gswz = (l >> 1) & 3;
        #pragma unroll
        for (int kg = 0; kg < 4; ++kg)
            *(short8v*)(gbase + l * 64 + ((kg ^ gswz) * 16)) = g8[kg];
        asm volatile("s_waitcnt lgkmcnt(0)" ::: "memory");
        __builtin_amdgcn_sched_barrier(0);
        #pragma unroll
        for (int q = 0; q < 4; ++q) {
            int row = q * 16 + (l & 15);
            int kgr = (l >> 4) ^ ((row >> 1) & 3);
            short8v afrag = *(const short8v*)(gbase + row * 64 + kgr * 16);
            acc[q] = __builtin_amdgcn_mfma_f32_16x16x32_bf16(afrag, bfrag[c2i], acc[q], 0, 0, 0);
        }
        asm volatile("s_waitcnt lgkmcnt(0)" ::: "memory");
        __builtin_amdgcn_sched_barrier(0);
    }

    float* cbuf = (float*)ldsW;
    {
        int h = l & 15, jg = l >> 4;
        #pragma unroll
        for (int q = 0; q < 4; ++q)
            *(float4v*)(cbuf + h * 68 + q * 16 + jg * 4) = acc[q];
    }
    asm volatile("s_waitcnt lgkmcnt(0)" ::: "memory");
    __builtin_amdgcn_sched_barrier(0);

    size_t obase = (((size_t)bi * NH) * L + i) * L + t;
    int bv = bonds[(((size_t)bi * L) + i) * L + t];
    float ninf = __uint_as_float(0xff7f0000u);
    bool pad = (a_j == 0);
    #pragma unroll
    for (int h = 0; h < NH; ++h) {
        float v = cbuf[h * 68 + l] + lin_b[h] + be[bv][h];
        out[obase + (size_t)h * L * L] = pad ? ninf : v;
    }
}

extern "C" void kernel_launch(void* const* d_in, const int* in_sizes, int n_in,
                              void* d_out, int out_size, void* d_ws, size_t ws_size,
                              hipStream_t stream) {
    const int*   atoms    = (const int*)d_in[0];
    const int*   chirals  = (const int*)d_in[1];
    const float* coords   = (const float*)d_in[2];
    const int*   bonds    = (const int*)d_in[3];
    const float* atype    = (const float*)d_in[4];
    const float* chiral   = (const float*)d_in[5];
    const float* wtab     = (const float*)d_in[6];
    const float* btab     = (const float*)d_in[7];
    const float* means    = (const float*)d_in[8];
    const float* stds     = (const float*)d_in[9];
    const float* bond_emb = (const float*)d_in[10];
    const float* lin_w    = (const float*)d_in[11];
    const float* lin_b    = (const float*)d_in[12];
    float* out = (float*)d_out;
    float* ws  = (float*)d_ws;

    if (ws_size >= WS_NEED) {
        setup_kernel<<<B * L, 256, 0, stream>>>(atoms, chirals, atype, chiral, wtab, btab,
                                                means, stds, lin_w, ws, out);
        pair_kernel_bf16<<<B * L, 256, 0, stream>>>(atoms, coords, bonds, bond_emb,
                                                    lin_b, ws, out + (size_t)EMB);
    } else {
        prep_kernel<<<1, 256, 0, stream>>>(means, stds, lin_w, ws);
        emb_kernel<<<B * L, 128, 0, stream>>>(atoms, chirals, atype, chiral, out);
        pair_kernel_f32<<<B * L, 256, 0, stream>>>(atoms, coords, bonds, wtab, btab,
                                                   bond_emb, lin_b, ws, out + (size_t)EMB);
    }
}

// Round 12
// 49.306 us; speedup vs baseline: 1.0890x; 1.0890x over previous
//
#include <hip/hip_runtime.h>
#include <hip/hip_bf16.h>
#include <math.h>
#include <stdint.h>

#define B 8
#define L 256
#define DM 512
#define NH 16
#define APO 128
#define VOC 128
#define EMB (L * B * DM)   // 1048576 floats

typedef __attribute__((ext_vector_type(8))) short short8v;   // 8 bf16 (4 VGPR)
typedef __attribute__((ext_vector_type(4))) float float4v;   // MFMA C/D

// ws layout (main path):
//   float[0..255]    : unused (fallback-compat offsets)
//   float[256..1280) : wsB = lw' B-fragments, ushort[2048] (bf16, mfma frag layout)
//   byte 6144 ..     : packed table, 16384 rows x 512 B:
//                      row r, chunk cc (16 k), pieces: [0,1]=w' halves, [2,3]=b' halves
//                      w' = w * beta/sigma_k ; b' = (b - mean_k) * beta/sigma_k  (bf16)
#define WSB_FOFF   256
#define PACK_BOFF  6144
#define PACK_BYTES (16384 * 512)
#define WS_NEED    ((size_t)PACK_BOFF + (size_t)PACK_BYTES)

__device__ __forceinline__ void g2lds16(const void* g, void* l) {
    __builtin_amdgcn_global_load_lds(
        (const __attribute__((address_space(1))) unsigned int*)g,
        (__attribute__((address_space(3))) unsigned int*)l, 16, 0, 0);
}

// ================= main path: setup (emb + table conversion + wsB) =============
__global__ __launch_bounds__(256) void setup_kernel(const int* __restrict__ atoms,
                                                    const int* __restrict__ chirals,
                                                    const float* __restrict__ atype,
                                                    const float* __restrict__ chiral,
                                                    const float* __restrict__ wtab,
                                                    const float* __restrict__ btab,
                                                    const float* __restrict__ means,
                                                    const float* __restrict__ stds,
                                                    const float* __restrict__ lin_w,
                                                    float* __restrict__ ws,
                                                    float* __restrict__ out) {
    int bid = blockIdx.x;          // 0..2047
    int t = threadIdx.x;
    const float beta = sqrtf(0.5f * 1.4426950408889634f);  // exp(-.5x^2)=exp2(-(x*beta)^2)
    const float gscale = 0.3989422804014327f;              // 1/sqrt(2*pi)

    // ---- emb for (bi,li) = bid (threads 0..127)
    if (t < 128) {
        int bi = bid >> 8, li = bid & 255;
        int a = atoms[bi * L + li];
        int c = chirals[bi * L + li];
        const float4* va = (const float4*)(atype + (size_t)a * DM);
        const float4* vc = (const float4*)(chiral + (size_t)c * DM);
        float4* vo = (float4*)(out + ((size_t)li * B + bi) * DM);
        float4 x = va[t], y = vc[t];
        x.x += y.x; x.y += y.y; x.z += y.z; x.w += y.w;
        vo[t] = x;
    }

    // ---- wsB (block 0): lw' in mfma_f32_16x16x32_bf16 B-frag layout
    if (bid == 0) {
        unsigned short* wsB = (unsigned short*)(ws + WSB_FOFF);
        for (int idx = t; idx < 4 * 64 * 8; idx += 256) {
            int c2 = idx >> 9;
            int lane = (idx >> 3) & 63;
            int e = idx & 7;
            int k = c2 * 32 + ((lane >> 4) << 3) + e;
            int h = lane & 15;
            float sigma = fabsf(stds[k]) + 1e-5f;
            float v = lin_w[k * NH + h] * (gscale / sigma);
            __hip_bfloat16 hb = __float2bfloat16(v);
            wsB[idx] = *reinterpret_cast<unsigned short*>(&hb);
        }
    }

    // ---- table conversion: one 16B piece (8 k) per thread
    int g = bid * 256 + t;          // 0..524287
    int row = g >> 5;               // 0..16383
    int p32 = g & 31;
    int cc = p32 >> 2, pp = p32 & 3;
    int k0 = cc * 16 + (pp & 1) * 8;
    const float* src = (pp < 2) ? wtab : btab;
    const float4* s4 = (const float4*)(src + (size_t)row * APO + k0);
    float4 v0 = s4[0], v1 = s4[1];
    const float* vv = (const float*)&v0;
    short8v o;
    #pragma unroll
    for (int e = 0; e < 8; ++e) {
        int k = k0 + e;
        float x = (e < 4) ? vv[e] : ((const float*)&v1)[e - 4];
        float sigma = fabsf(stds[k]) + 1e-5f;
        float ia = beta / sigma;
        float val = (pp < 2) ? x * ia : (x - means[k]) * ia;
        __hip_bfloat16 hb = __float2bfloat16(val);
        o[e] = *reinterpret_cast<short*>(&hb);
    }
    char* pk = (char*)ws + PACK_BOFF;
    *(short8v*)(pk + (size_t)row * 512 + cc * 64 + pp * 16) = o;
}

// ================= main path: pair kernel ======================================
// Row-universe staging: for block (b,i) only 128 distinct table rows exist
// (a*VOC + a_i, a=0..127) = 64KB. Stage them ALL once (coalesced
// global_load_lds, piece-XOR-swizzled), then the entire 128-k loop runs from
// LDS with no global latency. be[] dropped from LDS (bond_emb read directly
// in the epilogue) so LDS = exactly 64KB -> 2 blocks/CU; one block's staging
// overlaps the other's compute.
__global__ __launch_bounds__(256) void pair_kernel_bf16(const int* __restrict__ atoms,
                                                        const float* __restrict__ coords,
                                                        const int* __restrict__ bonds,
                                                        const float* __restrict__ bond_emb,
                                                        const float* __restrict__ lin_b,
                                                        const float* __restrict__ ws,
                                                        float* __restrict__ out) {
    __shared__ __align__(16) char rows[64 * 1024];   // 128 rows x 512B, swizzled

    int t = threadIdx.x;            // j
    int bid = blockIdx.x;           // bi*256 + i
    int bi = bid >> 8, i = bid & 255;
    int w = t >> 6, l = t & 63;

    int a_i = atoms[bi * L + i];    // wave-uniform
    const char* pk = (const char*)ws + PACK_BOFF;

    // ---- stage: wave w owns rows [w*32, w*32+32), 2 rows (1KB) per g2lds16.
    // LDS slot s of row a holds global piece s ^ (a&7) (involutive swizzle).
    {
        int p_slot = l & 31;
        int rh = l >> 5;            // 0/1: which of the pair's rows this lane serves
        #pragma unroll
        for (int it = 0; it < 16; ++it) {
            int a = w * 32 + it * 2 + rh;
            int p_src = p_slot ^ (a & 7);
            const char* g = pk + ((size_t)a * VOC + a_i) * 512 + (size_t)p_src * 16;
            char* dst = rows + (size_t)(w * 32 + it * 2) * 512;  // wave-uniform base
            g2lds16(g, dst);
        }
    }

    // ---- per-thread setup while staging flies
    float cix = coords[((size_t)bi * L + i) * 3 + 0];
    float ciy = coords[((size_t)bi * L + i) * 3 + 1];
    float ciz = coords[((size_t)bi * L + i) * 3 + 2];
    float cjx = coords[((size_t)bi * L + t) * 3 + 0];
    float cjy = coords[((size_t)bi * L + t) * 3 + 1];
    float cjz = coords[((size_t)bi * L + t) * 3 + 2];
    float dx = cjx - cix, dy = cjy - ciy, dz = cjz - ciz;
    float s2 = dx * dx + dy * dy + dz * dz;
    float d = (s2 > 0.0f) ? sqrtf(s2) : 0.0f;

    // d of the 4 rows this lane's A-frags cover (wave-local row r owned by lane r)
    int dbits = __float_as_int(d);
    float dval[4];
    #pragma unroll
    for (int q = 0; q < 4; ++q)
        dval[q] = __int_as_float(
            __builtin_amdgcn_ds_bpermute((q * 16 + (l & 15)) * 4, dbits));

    // LDS read bases: A-frag q covers j-row jq -> atom a; this lane's k-group
    // m=l>>4 reads piece pw0+8r (w) / pw0+2+8r (b), slot = piece ^ (a&7).
    int m = l >> 4;
    int pw0 = ((m >> 1) << 2) + (m & 1);        // {0,1,4,5}
    int baseW[4], baseB[4];
    #pragma unroll
    for (int q = 0; q < 4; ++q) {
        int jq = w * 64 + q * 16 + (l & 15);
        int a = atoms[bi * L + jq];
        int swz = a & 7;
        baseW[q] = a * 512 + ((pw0 ^ swz) << 4);
        baseB[q] = a * 512 + (((pw0 + 2) ^ swz) << 4);
    }

    const unsigned short* wsB = (const unsigned short*)(ws + WSB_FOFF);
    short8v bfrag[4];
    #pragma unroll
    for (int c2 = 0; c2 < 4; ++c2)
        bfrag[c2] = *(const short8v*)(wsB + ((size_t)c2 * 64 + l) * 8);

    float4v acc[4];
    #pragma unroll
    for (int q = 0; q < 4; ++q) { float4v z = {0, 0, 0, 0}; acc[q] = z; }

    asm volatile("s_waitcnt vmcnt(0)" ::: "memory");
    __syncthreads();                // rows[] ready for the whole block

    // ---- compute: pure LDS + VALU + MFMA, no global ops, no barriers
    #pragma unroll
    for (int r = 0; r < 4; ++r) {   // 4 rounds x 32 k
        #pragma unroll
        for (int q = 0; q < 4; ++q) {
            uint4 wv = *(const uint4*)(rows + baseW[q] + r * 128);
            uint4 bv = *(const uint4*)(rows + baseB[q] + r * 128);
            float dq = dval[q];
            short8v af;
            #pragma unroll
            for (int e2 = 0; e2 < 4; ++e2) {
                unsigned wd = ((const unsigned*)&wv)[e2];
                unsigned bd = ((const unsigned*)&bv)[e2];
                float wl = __uint_as_float(wd << 16);
                float wh = __uint_as_float(wd & 0xffff0000u);
                float bl = __uint_as_float(bd << 16);
                float bh = __uint_as_float(bd & 0xffff0000u);
                float tl = fmaf(wl, dq, bl);
                float th = fmaf(wh, dq, bh);
                float gl = __builtin_amdgcn_exp2f(-(tl * tl));
                float gh = __builtin_amdgcn_exp2f(-(th * th));
                __hip_bfloat16 hl = __float2bfloat16(gl);
                __hip_bfloat16 hh = __float2bfloat16(gh);
                af[2 * e2]     = *reinterpret_cast<short*>(&hl);
                af[2 * e2 + 1] = *reinterpret_cast<short*>(&hh);
            }
            acc[q] = __builtin_amdgcn_mfma_f32_16x16x32_bf16(af, bfrag[r], acc[q], 0, 0, 0);
        }
    }

    asm volatile("s_waitcnt lgkmcnt(0)" ::: "memory");
    __syncthreads();                // all reads of rows[] done -> reuse as cbuf

    // ---- epilogue: transpose C through reused staging LDS.
    // C layout (m89): col h = l&15, row j = 16q + (l>>4)*4 + reg.
    int a_j = atoms[bi * L + t];
    int bvd = bonds[(((size_t)bi * L) + i) * L + t];
    float beh[NH];
    {
        const float4* ber = (const float4*)(bond_emb + (size_t)bvd * NH);
        #pragma unroll
        for (int u = 0; u < 4; ++u) {
            float4 v4 = ber[u];
            beh[u * 4 + 0] = v4.x; beh[u * 4 + 1] = v4.y;
            beh[u * 4 + 2] = v4.z; beh[u * 4 + 3] = v4.w;
        }
    }
    float* cbuf = (float*)(rows + (size_t)w * 4352);   // 16 x 68 floats
    {
        int h = l & 15, jg = l >> 4;
        #pragma unroll
        for (int q = 0; q < 4; ++q)
            *(float4v*)(cbuf + h * 68 + q * 16 + jg * 4) = acc[q];
    }
    asm volatile("s_waitcnt lgkmcnt(0)" ::: "memory");
    __builtin_amdgcn_sched_barrier(0);

    size_t obase = (((size_t)bi * NH) * L + i) * L + t;
    // PAD column -> most-negative FINITE bf16 (0xff7f0000); survives harness bf16 cast.
    float ninf = __uint_as_float(0xff7f0000u);
    bool pad = (a_j == 0);
    #pragma unroll
    for (int h = 0; h < NH; ++h) {
        float v = cbuf[h * 68 + l] + lin_b[h] + beh[h];
        out[obase + (size_t)h * L * L] = pad ? ninf : v;
    }
}

// ================= fallback path (r6, verified) ================================
__global__ __launch_bounds__(128) void emb_kernel(const int* __restrict__ atoms,
                                                  const int* __restrict__ chirals,
                                                  const float* __restrict__ atype,
                                                  const float* __restrict__ chiral,
                                                  float* __restrict__ out) {
    int bid = blockIdx.x;
    int bi = bid >> 8, li = bid & 255;
    int a = atoms[bi * L + li];
    int c = chirals[bi * L + li];
    const float4* va = (const float4*)(atype + (size_t)a * DM);
    const float4* vc = (const float4*)(chiral + (size_t)c * DM);
    float4* vo = (float4*)(out + ((size_t)li * B + bi) * DM);
    int t = threadIdx.x;
    float4 x = va[t], y = vc[t];
    x.x += y.x; x.y += y.y; x.z += y.z; x.w += y.w;
    vo[t] = x;
}

__global__ __launch_bounds__(256) void prep_kernel(const float* __restrict__ means,
                                                   const float* __restrict__ stds,
                                                   const float* __restrict__ lin_w,
                                                   float* __restrict__ ws) {
    int t = threadIdx.x;
    const float beta = sqrtf(0.5f * 1.4426950408889634f);
    const float gscale = 0.3989422804014327f;
    if (t < APO) {
        float sigma = fabsf(stds[t]) + 1e-5f;
        float inv = 1.0f / sigma;
        ws[t] = inv * beta;
        ws[APO + t] = -means[t] * inv * beta;
    }
    unsigned short* wsB = (unsigned short*)(ws + 2 * APO);
    for (int idx = t; idx < 4 * 64 * 8; idx += 256) {
        int c2 = idx >> 9;
        int lane = (idx >> 3) & 63;
        int e = idx & 7;
        int k = c2 * 32 + ((lane >> 4) << 3) + e;
        int h = lane & 15;
        float sigma = fabsf(stds[k]) + 1e-5f;
        float v = lin_w[k * NH + h] * (gscale / sigma);
        __hip_bfloat16 hb = __float2bfloat16(v);
        wsB[idx] = *reinterpret_cast<unsigned short*>(&hb);
    }
}

__global__ __launch_bounds__(256) void pair_kernel_f32(const int* __restrict__ atoms,
                                                       const float* __restrict__ coords,
                                                       const int* __restrict__ bonds,
                                                       const float* __restrict__ wtab,
                                                       const float* __restrict__ btab,
                                                       const float* __restrict__ bond_emb,
                                                       const float* __restrict__ lin_b,
                                                       const float* __restrict__ ws,
                                                       float* __restrict__ out) {
    __shared__ float be[32][17];
    __shared__ __align__(16) char lds_raw[32 * 1024];
    __shared__ __align__(16) char lds_g[16 * 1024];

    int t = threadIdx.x;
    int bid = blockIdx.x;
    int bi = bid >> 8, i = bid & 255;
    int w = t >> 6, l = t & 63;

    for (int idx = t; idx < 32 * NH; idx += 256)
        be[idx >> 4][idx & 15] = bond_emb[idx];
    __syncthreads();

    int a_i = atoms[bi * L + i];
    int a_j = atoms[bi * L + t];

    float cix = coords[((size_t)bi * L + i) * 3 + 0];
    float ciy = coords[((size_t)bi * L + i) * 3 + 1];
    float ciz = coords[((size_t)bi * L + i) * 3 + 2];
    float cjx = coords[((size_t)bi * L + t) * 3 + 0];
    float cjy = coords[((size_t)bi * L + t) * 3 + 1];
    float cjz = coords[((size_t)bi * L + t) * 3 + 2];
    float dx = cjx - cix, dy = cjy - ciy, dz = cjz - ciz;
    float s2 = dx * dx + dy * dy + dz * dz;
    float d = (s2 > 0.0f) ? sqrtf(s2) : 0.0f;

    char* ldsW = lds_raw + (size_t)w * 8192;
    char* ldsB_ = ldsW + 4096;
    char* gbase = lds_g + (size_t)w * 4096;
    const char* wt = (const char*)wtab;
    const char* bt = (const char*)btab;
    size_t goff[4];
    #pragma unroll
    for (int q = 0; q < 4; ++q) {
        int r = q * 16 + (l >> 2);
        int ajr = atoms[bi * L + (w * 64 + r)];
        int row = ajr * VOC + a_i;
        int piece = (l & 3) ^ ((r >> 1) & 3);
        goff[q] = (size_t)row * (APO * 4) + (size_t)piece * 16;
    }
    int ss = (l >> 1) & 3;

    const float* ia = ws;
    const float* c2c = ws + APO;
    const unsigned short* wsB = (const unsigned short*)(ws + 2 * APO);
    short8v bfrag[4];
    #pragma unroll
    for (int c2 = 0; c2 < 4; ++c2)
        bfrag[c2] = *(const short8v*)(wsB + ((size_t)c2 * 64 + l) * 8);

    float4v acc[4];
    #pragma unroll
    for (int q = 0; q < 4; ++q) { float4v z = {0,0,0,0}; acc[q] = z; }

    #pragma unroll
    for (int c2i = 0; c2i < 4; ++c2i) {
        short8v g8[4];
        #pragma unroll
        for (int s = 0; s < 2; ++s) {
            int cc = c2i * 2 + s;
            #pragma unroll
            for (int q = 0; q < 4; ++q) {
                g2lds16(wt + goff[q] + cc * 64, ldsW + q * 1024);
                g2lds16(bt + goff[q] + cc * 64, ldsB_ + q * 1024);
            }
            asm volatile("s_waitcnt vmcnt(0)" ::: "memory");
            __builtin_amdgcn_sched_barrier(0);
            #pragma unroll
            for (int p = 0; p < 4; ++p) {
                int u = p ^ ss;
                float4 w4 = *(const float4*)(ldsW + l * 64 + u * 16);
                float4 b4 = *(const float4*)(ldsB_ + l * 64 + u * 16);
                const float* wp = (const float*)&w4;
                const float* bp = (const float*)&b4;
                #pragma unroll
                for (int uu = 0; uu < 4; ++uu) {
                    int kk = s * 16 + p * 4 + uu;
                    int k = c2i * 32 + kk;
                    float tt = fmaf(wp[uu], d, bp[uu]);
                    tt = fmaf(tt, ia[k], c2c[k]);
                    float g = __builtin_amdgcn_exp2f(-(tt * tt));
                    __hip_bfloat16 hb = __float2bfloat16(g);
                    g8[kk >> 3][kk & 7] = *reinterpret_cast<short*>(&hb);
                }
            }
            asm volatile("s_waitcnt lgkmcnt(0)" ::: "memory");
            __builtin_amdgcn_sched_barrier(0);
        }
        int gswz = (l >> 1) & 3;
        #pragma unroll
        for (int kg = 0; kg < 4; ++kg)
            *(short8v*)(gbase + l * 64 + ((kg ^ gswz) * 16)) = g8[kg];
        asm volatile("s_waitcnt lgkmcnt(0)" ::: "memory");
        __builtin_amdgcn_sched_barrier(0);
        #pragma unroll
        for (int q = 0; q < 4; ++q) {
            int row = q * 16 + (l & 15);
            int kgr = (l >> 4) ^ ((row >> 1) & 3);
            short8v afrag = *(const short8v*)(gbase + row * 64 + kgr * 16);
            acc[q] = __builtin_amdgcn_mfma_f32_16x16x32_bf16(afrag, bfrag[c2i], acc[q], 0, 0, 0);
        }
        asm volatile("s_waitcnt lgkmcnt(0)" ::: "memory");
        __builtin_amdgcn_sched_barrier(0);
    }

    float* cbuf = (float*)ldsW;
    {
        int h = l & 15, jg = l >> 4;
        #pragma unroll
        for (int q = 0; q < 4; ++q)
            *(float4v*)(cbuf + h * 68 + q * 16 + jg * 4) = acc[q];
    }
    asm volatile("s_waitcnt lgkmcnt(0)" ::: "memory");
    __builtin_amdgcn_sched_barrier(0);

    size_t obase = (((size_t)bi * NH) * L + i) * L + t;
    int bv = bonds[(((size_t)bi * L) + i) * L + t];
    float ninf = __uint_as_float(0xff7f0000u);
    bool pad = (a_j == 0);
    #pragma unroll
    for (int h = 0; h < NH; ++h) {
        float v = cbuf[h * 68 + l] + lin_b[h] + be[bv][h];
        out[obase + (size_t)h * L * L] = pad ? ninf : v;
    }
}

extern "C" void kernel_launch(void* const* d_in, const int* in_sizes, int n_in,
                              void* d_out, int out_size, void* d_ws, size_t ws_size,
                              hipStream_t stream) {
    const int*   atoms    = (const int*)d_in[0];
    const int*   chirals  = (const int*)d_in[1];
    const float* coords   = (const float*)d_in[2];
    const int*   bonds    = (const int*)d_in[3];
    const float* atype    = (const float*)d_in[4];
    const float* chiral   = (const float*)d_in[5];
    const float* wtab     = (const float*)d_in[6];
    const float* btab     = (const float*)d_in[7];
    const float* means    = (const float*)d_in[8];
    const float* stds     = (const float*)d_in[9];
    const float* bond_emb = (const float*)d_in[10];
    const float* lin_w    = (const float*)d_in[11];
    const float* lin_b    = (const float*)d_in[12];
    float* out = (float*)d_out;
    float* ws  = (float*)d_ws;

    if (ws_size >= WS_NEED) {
        setup_kernel<<<B * L, 256, 0, stream>>>(atoms, chirals, atype, chiral, wtab, btab,
                                                means, stds, lin_w, ws, out);
        pair_kernel_bf16<<<B * L, 256, 0, stream>>>(atoms, coords, bonds, bond_emb,
                                                    lin_b, ws, out + (size_t)EMB);
    } else {
        prep_kernel<<<1, 256, 0, stream>>>(means, stds, lin_w, ws);
        emb_kernel<<<B * L, 128, 0, stream>>>(atoms, chirals, atype, chiral, out);
        pair_kernel_f32<<<B * L, 256, 0, stream>>>(atoms, coords, bonds, wtab, btab,
                                                   bond_emb, lin_b, ws, out + (size_t)EMB);
    }
}

// Round 13
// 44.344 us; speedup vs baseline: 1.2109x; 1.1119x over previous
//
#include <hip/hip_runtime.h>
#include <hip/hip_bf16.h>
#include <math.h>
#include <stdint.h>

#define B 8
#define L 256
#define DM 512
#define NH 16
#define APO 128
#define VOC 128
#define EMB (L * B * DM)   // 1048576 floats

typedef __attribute__((ext_vector_type(8))) short short8v;   // 8 bf16 (4 VGPR)
typedef __attribute__((ext_vector_type(4))) float float4v;   // MFMA C/D

// ws layout (main path):
//   float[0..255]    : unused (fallback-compat offsets)
//   float[256..1280) : wsB = lw' B-fragments, ushort[2048] (bf16, mfma frag layout)
//   byte 6144 ..     : packed table, 16384 rows x 512 B (32 pieces of 16B):
//                      chunk cc (16 k) = pieces [4cc,4cc+1]=w' halves, [4cc+2,4cc+3]=b'
//                      w' = w * beta/sigma_k ; b' = (b - mean_k) * beta/sigma_k  (bf16)
#define WSB_FOFF   256
#define PACK_BOFF  6144
#define PACK_BYTES (16384 * 512)
#define WS_NEED    ((size_t)PACK_BOFF + (size_t)PACK_BYTES)

__device__ __forceinline__ void g2lds16(const void* g, void* l) {
    __builtin_amdgcn_global_load_lds(
        (const __attribute__((address_space(1))) unsigned int*)g,
        (__attribute__((address_space(3))) unsigned int*)l, 16, 0, 0);
}

// ================= main path: setup (emb + table conversion + wsB) =============
__global__ __launch_bounds__(256) void setup_kernel(const int* __restrict__ atoms,
                                                    const int* __restrict__ chirals,
                                                    const float* __restrict__ atype,
                                                    const float* __restrict__ chiral,
                                                    const float* __restrict__ wtab,
                                                    const float* __restrict__ btab,
                                                    const float* __restrict__ means,
                                                    const float* __restrict__ stds,
                                                    const float* __restrict__ lin_w,
                                                    float* __restrict__ ws,
                                                    float* __restrict__ out) {
    int bid = blockIdx.x;          // 0..2047
    int t = threadIdx.x;
    const float beta = sqrtf(0.5f * 1.4426950408889634f);  // exp(-.5x^2)=exp2(-(x*beta)^2)
    const float gscale = 0.3989422804014327f;              // 1/sqrt(2*pi)

    // ---- emb for (bi,li) = bid (threads 0..127)
    if (t < 128) {
        int bi = bid >> 8, li = bid & 255;
        int a = atoms[bi * L + li];
        int c = chirals[bi * L + li];
        const float4* va = (const float4*)(atype + (size_t)a * DM);
        const float4* vc = (const float4*)(chiral + (size_t)c * DM);
        float4* vo = (float4*)(out + ((size_t)li * B + bi) * DM);
        float4 x = va[t], y = vc[t];
        x.x += y.x; x.y += y.y; x.z += y.z; x.w += y.w;
        vo[t] = x;
    }

    // ---- wsB (block 0): lw' in mfma_f32_16x16x32_bf16 B-frag layout
    if (bid == 0) {
        unsigned short* wsB = (unsigned short*)(ws + WSB_FOFF);
        for (int idx = t; idx < 4 * 64 * 8; idx += 256) {
            int c2 = idx >> 9;
            int lane = (idx >> 3) & 63;
            int e = idx & 7;
            int k = c2 * 32 + ((lane >> 4) << 3) + e;
            int h = lane & 15;
            float sigma = fabsf(stds[k]) + 1e-5f;
            float v = lin_w[k * NH + h] * (gscale / sigma);
            __hip_bfloat16 hb = __float2bfloat16(v);
            wsB[idx] = *reinterpret_cast<unsigned short*>(&hb);
        }
    }

    // ---- table conversion: one 16B piece (8 k) per thread
    int g = bid * 256 + t;          // 0..524287
    int row = g >> 5;               // 0..16383
    int p32 = g & 31;
    int cc = p32 >> 2, pp = p32 & 3;
    int k0 = cc * 16 + (pp & 1) * 8;
    const float* src = (pp < 2) ? wtab : btab;
    const float4* s4 = (const float4*)(src + (size_t)row * APO + k0);
    float4 v0 = s4[0], v1 = s4[1];
    const float* vv = (const float*)&v0;
    short8v o;
    #pragma unroll
    for (int e = 0; e < 8; ++e) {
        int k = k0 + e;
        float x = (e < 4) ? vv[e] : ((const float*)&v1)[e - 4];
        float sigma = fabsf(stds[k]) + 1e-5f;
        float ia = beta / sigma;
        float val = (pp < 2) ? x * ia : (x - means[k]) * ia;
        __hip_bfloat16 hb = __float2bfloat16(val);
        o[e] = *reinterpret_cast<short*>(&hb);
    }
    char* pk = (char*)ws + PACK_BOFF;
    *(short8v*)(pk + (size_t)row * 512 + cc * 64 + pp * 16) = o;
}

// ================= main path: pair kernel ======================================
// Row-universe staging, 2 passes: for block (b,i) only 128 distinct table rows
// exist (a*VOC + a_i). Stage the pass's 256B half-rows (32KB total) coalesced
// via global_load_lds (4-bit piece-XOR swizzle), compute 2 MFMA rounds from
// LDS, barrier, repeat. LDS = 32KB -> 5 blocks/CU: inter-block TLP hides the
// stage drains and barriers that 64KB/2-block r12 exposed.
__global__ __launch_bounds__(256) void pair_kernel_bf16(const int* __restrict__ atoms,
                                                        const float* __restrict__ coords,
                                                        const int* __restrict__ bonds,
                                                        const float* __restrict__ bond_emb,
                                                        const float* __restrict__ lin_b,
                                                        const float* __restrict__ ws,
                                                        float* __restrict__ out) {
    __shared__ __align__(16) char rows[32 * 1024];   // 128 rows x 256B (pass half)

    int t = threadIdx.x;            // j
    int bid = blockIdx.x;           // bi*256 + i
    int bi = bid >> 8, i = bid & 255;
    int w = t >> 6, l = t & 63;

    int a_i = atoms[bi * L + i];    // wave-uniform
    const char* pk = (const char*)ws + PACK_BOFF;

    // staging lane roles: instruction 'it' covers rows [w*32+it*4, +4);
    // lane l serves row +(l>>4), LDS slot l&15 <- global piece
    // pass*16 + ((l&15) ^ (a&15))  (involutive 4-bit swizzle)
    int s_rq = l >> 4, s_sl = l & 15;

    // ---- pass-0 staging issued first, everything else overlaps the flight
    #pragma unroll
    for (int it = 0; it < 8; ++it) {
        int a = w * 32 + it * 4 + s_rq;
        const char* g = pk + ((size_t)(a * VOC + a_i)) * 512
                        + (size_t)((s_sl ^ (a & 15))) * 16;
        g2lds16(g, rows + (size_t)(w * 32 + it * 4) * 256);
    }

    float cix = coords[((size_t)bi * L + i) * 3 + 0];
    float ciy = coords[((size_t)bi * L + i) * 3 + 1];
    float ciz = coords[((size_t)bi * L + i) * 3 + 2];
    float cjx = coords[((size_t)bi * L + t) * 3 + 0];
    float cjy = coords[((size_t)bi * L + t) * 3 + 1];
    float cjz = coords[((size_t)bi * L + t) * 3 + 2];
    float dx = cjx - cix, dy = cjy - ciy, dz = cjz - ciz;
    float s2 = dx * dx + dy * dy + dz * dz;
    float d = (s2 > 0.0f) ? sqrtf(s2) : 0.0f;

    // d of the 4 rows this lane's A-frags cover (wave-local lane r = row r)
    int dbits = __float_as_int(d);
    float dval[4];
    #pragma unroll
    for (int q = 0; q < 4; ++q)
        dval[q] = __int_as_float(
            __builtin_amdgcn_ds_bpermute((q * 16 + (l & 15)) * 4, dbits));

    // compute-side LDS offsets: A-frag q covers j-row jq -> atom a;
    // lane k-group m needs pass-local pieces r2*8+pw0 (w) / +2 (b),
    // at slot = piece ^ (a&15).
    int m = l >> 4;
    int pw0 = ((m >> 1) << 2) + (m & 1);        // {0,1,4,5}
    int woff[4][2], boff[4][2];
    #pragma unroll
    for (int q = 0; q < 4; ++q) {
        int jq = w * 64 + q * 16 + (l & 15);
        int a = atoms[bi * L + jq];
        int swz = a & 15;
        int ab = a * 256;
        #pragma unroll
        for (int r2 = 0; r2 < 2; ++r2) {
            woff[q][r2] = ab + (((r2 * 8 + pw0) ^ swz) << 4);
            boff[q][r2] = ab + (((r2 * 8 + pw0 + 2) ^ swz) << 4);
        }
    }

    const unsigned short* wsB = (const unsigned short*)(ws + WSB_FOFF);
    short8v bfrag[4];
    #pragma unroll
    for (int c2 = 0; c2 < 4; ++c2)
        bfrag[c2] = *(const short8v*)(wsB + ((size_t)c2 * 64 + l) * 8);

    float4v acc[4];
    #pragma unroll
    for (int q = 0; q < 4; ++q) { float4v z = {0, 0, 0, 0}; acc[q] = z; }

#define COMPUTE_ROUND(rr, r2)                                                   \
    {                                                                           \
        _Pragma("unroll")                                                       \
        for (int q = 0; q < 4; ++q) {                                           \
            uint4 wv = *(const uint4*)(rows + woff[q][r2]);                     \
            uint4 bv = *(const uint4*)(rows + boff[q][r2]);                     \
            float dq = dval[q];                                                 \
            uint4 afu;                                                          \
            _Pragma("unroll")                                                   \
            for (int e2 = 0; e2 < 4; ++e2) {                                    \
                unsigned wd = ((const unsigned*)&wv)[e2];                       \
                unsigned bd = ((const unsigned*)&bv)[e2];                       \
                float wl = __uint_as_float(wd << 16);                           \
                float wh = __uint_as_float(wd & 0xffff0000u);                   \
                float bl = __uint_as_float(bd << 16);                           \
                float bh = __uint_as_float(bd & 0xffff0000u);                   \
                float tl = fmaf(wl, dq, bl);                                    \
                float th = fmaf(wh, dq, bh);                                    \
                float gl = __builtin_amdgcn_exp2f(-(tl * tl));                  \
                float gh = __builtin_amdgcn_exp2f(-(th * th));                  \
                unsigned glb = __float_as_uint(gl) + 0x8000u;                   \
                unsigned ghb = __float_as_uint(gh) + 0x8000u;                   \
                ((unsigned*)&afu)[e2] = (ghb & 0xffff0000u) | (glb >> 16);      \
            }                                                                   \
            short8v af = *reinterpret_cast<short8v*>(&afu);                     \
            acc[q] = __builtin_amdgcn_mfma_f32_16x16x32_bf16(af, bfrag[rr],     \
                                                             acc[q], 0, 0, 0); \
        }                                                                       \
    }

    // ---- pass 0
    asm volatile("s_waitcnt vmcnt(0)" ::: "memory");
    __syncthreads();
    COMPUTE_ROUND(0, 0)
    COMPUTE_ROUND(1, 1)
    asm volatile("s_waitcnt lgkmcnt(0)" ::: "memory");
    __syncthreads();                // everyone done reading pass-0 rows

    // ---- pass 1 staging
    #pragma unroll
    for (int it = 0; it < 8; ++it) {
        int a = w * 32 + it * 4 + s_rq;
        const char* g = pk + ((size_t)(a * VOC + a_i)) * 512 + 256
                        + (size_t)((s_sl ^ (a & 15))) * 16;
        g2lds16(g, rows + (size_t)(w * 32 + it * 4) * 256);
    }
    asm volatile("s_waitcnt vmcnt(0)" ::: "memory");
    __syncthreads();
    COMPUTE_ROUND(2, 0)
    COMPUTE_ROUND(3, 1)
    asm volatile("s_waitcnt lgkmcnt(0)" ::: "memory");
    __syncthreads();                // reads done -> reuse rows as cbuf
#undef COMPUTE_ROUND

    // ---- epilogue: transpose C through reused staging LDS.
    // C layout (m89): col h = l&15, row j = 16q + (l>>4)*4 + reg.
    int a_j = atoms[bi * L + t];
    int bvd = bonds[(((size_t)bi * L) + i) * L + t];
    float beh[NH];
    {
        const float4* ber = (const float4*)(bond_emb + (size_t)bvd * NH);
        #pragma unroll
        for (int u = 0; u < 4; ++u) {
            float4 v4 = ber[u];
            beh[u * 4 + 0] = v4.x; beh[u * 4 + 1] = v4.y;
            beh[u * 4 + 2] = v4.z; beh[u * 4 + 3] = v4.w;
        }
    }
    float* cbuf = (float*)(rows + (size_t)w * 4352);   // 16 x 68 floats/wave
    {
        int h = l & 15, jg = l >> 4;
        #pragma unroll
        for (int q = 0; q < 4; ++q)
            *(float4v*)(cbuf + h * 68 + q * 16 + jg * 4) = acc[q];
    }
    asm volatile("s_waitcnt lgkmcnt(0)" ::: "memory");
    __builtin_amdgcn_sched_barrier(0);

    size_t obase = (((size_t)bi * NH) * L + i) * L + t;
    // PAD column -> most-negative FINITE bf16 (0xff7f0000); survives harness bf16 cast.
    float ninf = __uint_as_float(0xff7f0000u);
    bool pad = (a_j == 0);
    #pragma unroll
    for (int h = 0; h < NH; ++h) {
        float v = cbuf[h * 68 + l] + lin_b[h] + beh[h];
        out[obase + (size_t)h * L * L] = pad ? ninf : v;
    }
}

// ================= fallback path (r6, verified) ================================
__global__ __launch_bounds__(128) void emb_kernel(const int* __restrict__ atoms,
                                                  const int* __restrict__ chirals,
                                                  const float* __restrict__ atype,
                                                  const float* __restrict__ chiral,
                                                  float* __restrict__ out) {
    int bid = blockIdx.x;
    int bi = bid >> 8, li = bid & 255;
    int a = atoms[bi * L + li];
    int c = chirals[bi * L + li];
    const float4* va = (const float4*)(atype + (size_t)a * DM);
    const float4* vc = (const float4*)(chiral + (size_t)c * DM);
    float4* vo = (float4*)(out + ((size_t)li * B + bi) * DM);
    int t = threadIdx.x;
    float4 x = va[t], y = vc[t];
    x.x += y.x; x.y += y.y; x.z += y.z; x.w += y.w;
    vo[t] = x;
}

__global__ __launch_bounds__(256) void prep_kernel(const float* __restrict__ means,
                                                   const float* __restrict__ stds,
                                                   const float* __restrict__ lin_w,
                                                   float* __restrict__ ws) {
    int t = threadIdx.x;
    const float beta = sqrtf(0.5f * 1.4426950408889634f);
    const float gscale = 0.3989422804014327f;
    if (t < APO) {
        float sigma = fabsf(stds[t]) + 1e-5f;
        float inv = 1.0f / sigma;
        ws[t] = inv * beta;
        ws[APO + t] = -means[t] * inv * beta;
    }
    unsigned short* wsB = (unsigned short*)(ws + 2 * APO);
    for (int idx = t; idx < 4 * 64 * 8; idx += 256) {
        int c2 = idx >> 9;
        int lane = (idx >> 3) & 63;
        int e = idx & 7;
        int k = c2 * 32 + ((lane >> 4) << 3) + e;
        int h = lane & 15;
        float sigma = fabsf(stds[k]) + 1e-5f;
        float v = lin_w[k * NH + h] * (gscale / sigma);
        __hip_bfloat16 hb = __float2bfloat16(v);
        wsB[idx] = *reinterpret_cast<unsigned short*>(&hb);
    }
}

__global__ __launch_bounds__(256) void pair_kernel_f32(const int* __restrict__ atoms,
                                                       const float* __restrict__ coords,
                                                       const int* __restrict__ bonds,
                                                       const float* __restrict__ wtab,
                                                       const float* __restrict__ btab,
                                                       const float* __restrict__ bond_emb,
                                                       const float* __restrict__ lin_b,
                                                       const float* __restrict__ ws,
                                                       float* __restrict__ out) {
    __shared__ float be[32][17];
    __shared__ __align__(16) char lds_raw[32 * 1024];
    __shared__ __align__(16) char lds_g[16 * 1024];

    int t = threadIdx.x;
    int bid = blockIdx.x;
    int bi = bid >> 8, i = bid & 255;
    int w = t >> 6, l = t & 63;

    for (int idx = t; idx < 32 * NH; idx += 256)
        be[idx >> 4][idx & 15] = bond_emb[idx];
    __syncthreads();

    int a_i = atoms[bi * L + i];
    int a_j = atoms[bi * L + t];

    float cix = coords[((size_t)bi * L + i) * 3 + 0];
    float ciy = coords[((size_t)bi * L + i) * 3 + 1];
    float ciz = coords[((size_t)bi * L + i) * 3 + 2];
    float cjx = coords[((size_t)bi * L + t) * 3 + 0];
    float cjy = coords[((size_t)bi * L + t) * 3 + 1];
    float cjz = coords[((size_t)bi * L + t) * 3 + 2];
    float dx = cjx - cix, dy = cjy - ciy, dz = cjz - ciz;
    float s2 = dx * dx + dy * dy + dz * dz;
    float d = (s2 > 0.0f) ? sqrtf(s2) : 0.0f;

    char* ldsW = lds_raw + (size_t)w * 8192;
    char* ldsB_ = ldsW + 4096;
    char* gbase = lds_g + (size_t)w * 4096;
    const char* wt = (const char*)wtab;
    const char* bt = (const char*)btab;
    size_t goff[4];
    #pragma unroll
    for (int q = 0; q < 4; ++q) {
        int r = q * 16 + (l >> 2);
        int ajr = atoms[bi * L + (w * 64 + r)];
        int row = ajr * VOC + a_i;
        int piece = (l & 3) ^ ((r >> 1) & 3);
        goff[q] = (size_t)row * (APO * 4) + (size_t)piece * 16;
    }
    int ss = (l >> 1) & 3;

    const float* ia = ws;
    const float* c2c = ws + APO;
    const unsigned short* wsB = (const unsigned short*)(ws + 2 * APO);
    short8v bfrag[4];
    #pragma unroll
    for (int c2 = 0; c2 < 4; ++c2)
        bfrag[c2] = *(const short8v*)(wsB + ((size_t)c2 * 64 + l) * 8);

    float4v acc[4];
    #pragma unroll
    for (int q = 0; q < 4; ++q) { float4v z = {0,0,0,0}; acc[q] = z; }

    #pragma unroll
    for (int c2i = 0; c2i < 4; ++c2i) {
        short8v g8[4];
        #pragma unroll
        for (int s = 0; s < 2; ++s) {
            int cc = c2i * 2 + s;
            #pragma unroll
            for (int q = 0; q < 4; ++q) {
                g2lds16(wt + goff[q] + cc * 64, ldsW + q * 1024);
                g2lds16(bt + goff[q] + cc * 64, ldsB_ + q * 1024);
            }
            asm volatile("s_waitcnt vmcnt(0)" ::: "memory");
            __builtin_amdgcn_sched_barrier(0);
            #pragma unroll
            for (int p = 0; p < 4; ++p) {
                int u = p ^ ss;
                float4 w4 = *(const float4*)(ldsW + l * 64 + u * 16);
                float4 b4 = *(const float4*)(ldsB_ + l * 64 + u * 16);
                const float* wp = (const float*)&w4;
                const float* bp = (const float*)&b4;
                #pragma unroll
                for (int uu = 0; uu < 4; ++uu) {
                    int kk = s * 16 + p * 4 + uu;
                    int k = c2i * 32 + kk;
                    float tt = fmaf(wp[uu], d, bp[uu]);
                    tt = fmaf(tt, ia[k], c2c[k]);
                    float g = __builtin_amdgcn_exp2f(-(tt * tt));
                    __hip_bfloat16 hb = __float2bfloat16(g);
                    g8[kk >> 3][kk & 7] = *reinterpret_cast<short*>(&hb);
                }
            }
            asm volatile("s_waitcnt lgkmcnt(0)" ::: "memory");
            __builtin_amdgcn_sched_barrier(0);
        }
        int gswz = (l >> 1) & 3;
        #pragma unroll
        for (int kg = 0; kg < 4; ++kg)
            *(short8v*)(gbase + l * 64 + ((kg ^ gswz) * 16)) = g8[kg];
        asm volatile("s_waitcnt lgkmcnt(0)" ::: "memory");
        __builtin_amdgcn_sched_barrier(0);
        #pragma unroll
        for (int q = 0; q < 4; ++q) {
            int row = q * 16 + (l & 15);
            int kgr = (l >> 4) ^ ((row >> 1) & 3);
            short8v afrag = *(const short8v*)(gbase + row * 64 + kgr * 16);
            acc[q] = __builtin_amdgcn_mfma_f32_16x16x32_bf16(afrag, bfrag[c2i], acc[q], 0, 0, 0);
        }
        asm volatile("s_waitcnt lgkmcnt(0)" ::: "memory");
        __builtin_amdgcn_sched_barrier(0);
    }

    float* cbuf = (float*)ldsW;
    {
        int h = l & 15, jg = l >> 4;
        #pragma unroll
        for (int q = 0; q < 4; ++q)
            *(float4v*)(cbuf + h * 68 + q * 16 + jg * 4) = acc[q];
    }
    asm volatile("s_waitcnt lgkmcnt(0)" ::: "memory");
    __builtin_amdgcn_sched_barrier(0);

    size_t obase = (((size_t)bi * NH) * L + i) * L + t;
    int bv = bonds[(((size_t)bi * L) + i) * L + t];
    float ninf = __uint_as_float(0xff7f0000u);
    bool pad = (a_j == 0);
    #pragma unroll
    for (int h = 0; h < NH; ++h) {
        float v = cbuf[h * 68 + l] + lin_b[h] + be[bv][h];
        out[obase + (size_t)h * L * L] = pad ? ninf : v;
    }
}

extern "C" void kernel_launch(void* const* d_in, const int* in_sizes, int n_in,
                              void* d_out, int out_size, void* d_ws, size_t ws_size,
                              hipStream_t stream) {
    const int*   atoms    = (const int*)d_in[0];
    const int*   chirals  = (const int*)d_in[1];
    const float* coords   = (const float*)d_in[2];
    const int*   bonds    = (const int*)d_in[3];
    const float* atype    = (const float*)d_in[4];
    const float* chiral   = (const float*)d_in[5];
    const float* wtab     = (const float*)d_in[6];
    const float* btab     = (const float*)d_in[7];
    const float* means    = (const float*)d_in[8];
    const float* stds     = (const float*)d_in[9];
    const float* bond_emb = (const float*)d_in[10];
    const float* lin_w    = (const float*)d_in[11];
    const float* lin_b    = (const float*)d_in[12];
    float* out = (float*)d_out;
    float* ws  = (float*)d_ws;

    if (ws_size >= WS_NEED) {
        setup_kernel<<<B * L, 256, 0, stream>>>(atoms, chirals, atype, chiral, wtab, btab,
                                                means, stds, lin_w, ws, out);
        pair_kernel_bf16<<<B * L, 256, 0, stream>>>(atoms, coords, bonds, bond_emb,
                                                    lin_b, ws, out + (size_t)EMB);
    } else {
        prep_kernel<<<1, 256, 0, stream>>>(means, stds, lin_w, ws);
        emb_kernel<<<B * L, 128, 0, stream>>>(atoms, chirals, atype, chiral, out);
        pair_kernel_f32<<<B * L, 256, 0, stream>>>(atoms, coords, bonds, wtab, btab,
                                                   bond_emb, lin_b, ws, out + (size_t)EMB);
    }
}